// Round 3
// baseline (544.909 us; speedup 1.0000x reference)
//
#include <hip/hip_runtime.h>

typedef unsigned int u32;
typedef unsigned short u16;
typedef short bf16x8 __attribute__((ext_vector_type(8)));   // 8 bf16 (4 VGPRs)
typedef float f32x4 __attribute__((ext_vector_type(4)));    // MFMA accumulator

__device__ __forceinline__ float bf2f(u16 h) { return __uint_as_float(((u32)h) << 16); }
__device__ __forceinline__ u16 f2bf(float f) {
    u32 u = __float_as_uint(f);
    return (u16)((u + 0x7fffu + ((u >> 16) & 1u)) >> 16);   // RNE
}

// ---------------- diagnostic fallback: ws too small ----------------
__global__ __launch_bounds__(256) void k_sentinel(u16* out, int n) {
    int i = blockIdx.x * 256 + threadIdx.x;
    if (i < n) out[i] = f2bf(-7.0f);
}

// ---------------- dtype detection: flag=0 bf16-packed, flag=1 f32 ----------------
// Low u16 of each u32: for bf16 pairs it's a bf16 of ~N(0,1) (exponent in range);
// for f32 it's uniform mantissa bits (exponent field uniform -> ~9% hits).
__global__ void k_detect(const u32* x, int* flag) {
    int lane = threadIdx.x;  // 64 threads
    int c = 0;
    for (int j = 0; j < 4; ++j) {
        u32 u = x[lane * 4 + j];
        u32 e = (u >> 7) & 0xffu;
        if ((e >= 0x30u && e <= 0x47u) || ((u & 0x7fffu) == 0u)) ++c;
    }
    for (int d = 32; d; d >>= 1) c += __shfl_down(c, d, 64);
    if (lane == 0) *flag = (c < 128) ? 1 : 0;
}

// ---------------- converters into canonical packed-bf16 / f32 ----------------
__global__ __launch_bounds__(256) void k_cvt(const void* src, const int* flag,
                                             u32* dst, int n) {  // n = u32 words out
    int i = blockIdx.x * 256 + threadIdx.x;
    if (i >= n) return;
    if (*flag) {
        const float* s = (const float*)src;
        dst[i] = (u32)f2bf(s[2 * i]) | ((u32)f2bf(s[2 * i + 1]) << 16);
    } else {
        dst[i] = ((const u32*)src)[i];
    }
}

__global__ __launch_bounds__(128) void k_cvt_bias(const void* src, const int* flag,
                                                  float* dst, int n) {
    int i = threadIdx.x;
    if (i >= n) return;
    if (*flag) dst[i] = ((const float*)src)[i];
    else       dst[i] = bf2f(((const u16*)src)[i]);
}

// ---------------- CSR build ----------------
__global__ __launch_bounds__(256) void k_deg(const int* dstv, int* deg, int E, int N) {
    int e = blockIdx.x * 256 + threadIdx.x;
    if (e >= E) return;
    int d = dstv[e]; d = min(max(d, 0), N - 1);
    atomicAdd(&deg[d], 1);
}

__global__ __launch_bounds__(512) void k_scan1(const int* deg, int* rowptr,
                                               int* bsums, int N) {
    __shared__ int sm[512];
    int i = blockIdx.x * 512 + threadIdx.x;
    int v = (i < N) ? deg[i] : 0;
    sm[threadIdx.x] = v;
    __syncthreads();
    for (int off = 1; off < 512; off <<= 1) {
        int t = (threadIdx.x >= off) ? sm[threadIdx.x - off] : 0;
        __syncthreads();
        sm[threadIdx.x] += t;
        __syncthreads();
    }
    if (i < N) rowptr[i] = sm[threadIdx.x] - v;            // exclusive
    if (threadIdx.x == 511) bsums[blockIdx.x] = sm[511];
}

__global__ __launch_bounds__(128) void k_scan2(int* bsums, int nb) {
    __shared__ int sm[128];
    int v = (threadIdx.x < nb) ? bsums[threadIdx.x] : 0;
    sm[threadIdx.x] = v;
    __syncthreads();
    for (int off = 1; off < 128; off <<= 1) {
        int t = (threadIdx.x >= off) ? sm[threadIdx.x - off] : 0;
        __syncthreads();
        sm[threadIdx.x] += t;
        __syncthreads();
    }
    if (threadIdx.x < nb) bsums[threadIdx.x] = sm[threadIdx.x] - v;  // exclusive
}

__global__ __launch_bounds__(512) void k_scan3(int* rowptr, const int* bsums,
                                               int N, int E) {
    int i = blockIdx.x * 512 + threadIdx.x;
    if (i < N) rowptr[i] += bsums[blockIdx.x];
    if (i == 0) rowptr[N] = E;
}

// deg doubles as countdown cursor (any slot order is fine for mean)
__global__ __launch_bounds__(256) void k_fill(const int* srcv, const int* dstv,
                                              const int* rowptr, int* deg,
                                              int* adj, int E, int N) {
    int e = blockIdx.x * 256 + threadIdx.x;
    if (e >= E) return;
    int d = dstv[e]; d = min(max(d, 0), N - 1);
    int slot = atomicSub(&deg[d], 1) - 1;
    int idx = rowptr[d] + slot;
    idx = min(max(idx, 0), E - 1);   // clamp: CSR bug => finite-wrong, not NaN
    adj[idx] = srcv[e];
}

// ---------------- mean aggregation: one wave per node ----------------
__global__ __launch_bounds__(256) void k_aggregate(const u32* F, const int* rowptr,
                                                   const int* adj, u32* A,
                                                   int N, int E) {
    int wid = (int)((blockIdx.x * 256u + threadIdx.x) >> 6);
    int lane = threadIdx.x & 63;
    if (wid >= N) return;
    int beg = rowptr[wid], end = rowptr[wid + 1];
    beg = min(max(beg, 0), E);
    end = min(max(end, beg), E);
    float s0 = 0.f, s1 = 0.f;
    for (int j = beg; j < end; ++j) {
        int a0 = adj[j];
        a0 = min(max(a0, 0), N - 1);  // clamp: bad adj => finite-wrong, not NaN
        u32 u = F[(size_t)a0 * 64 + lane];
        s0 += __uint_as_float(u << 16);
        s1 += __uint_as_float(u & 0xffff0000u);
    }
    float d = fmaxf((float)(end - beg), 1.f);
    A[(size_t)wid * 64 + lane] = (u32)f2bf(s0 / d) | ((u32)f2bf(s1 / d) << 16);
}

// ---------------- fused SAGE GEMM: h = act(Agg@Wl^T + b + Xin@Wr^T) ----------------
// One wave per 16-node tile; K=256 (agg||x vs Wl||Wr), 8 col-tiles.
// Each wave reads only its own 16 rows fully into regs before storing those same
// rows -> Out may alias Agg or Xin. (No __restrict__: aliasing is intentional.)
template <int ACT>  // 0 = relu, 1 = elu
__global__ __launch_bounds__(256) void k_gemm128(const u16* Agg, const u16* Xin,
                                                 const u32* Wl, const u32* Wr,
                                                 const float* bias, u16* Out, int N) {
    int tile = blockIdx.x * 4 + (threadIdx.x >> 6);
    int lane = threadIdx.x & 63;
    int m0 = tile * 16;
    if (m0 >= N) return;
    int mrow = m0 + (lane & 15);
    int kq = (lane >> 4) * 8;

    bf16x8 afrag[8];
#pragma unroll
    for (int s = 0; s < 8; ++s) {
        int k = s * 32 + kq;
        const u16* p = (k < 128) ? (Agg + (size_t)mrow * 128 + k)
                                 : (Xin + (size_t)mrow * 128 + (k - 128));
        afrag[s] = *(const bf16x8*)p;
    }

    f32x4 acc[8];
#pragma unroll
    for (int c = 0; c < 8; ++c) acc[c] = (f32x4){0.f, 0.f, 0.f, 0.f};

#pragma unroll
    for (int c = 0; c < 8; ++c) {
        int o = c * 16 + (lane & 15);
#pragma unroll
        for (int s = 0; s < 8; ++s) {
            int k = s * 32 + kq;
            const u32* p = (k < 128) ? (Wl + ((size_t)o * 128 + k) / 2)
                                     : (Wr + ((size_t)o * 128 + (k - 128)) / 2);
            bf16x8 b = *(const bf16x8*)p;
            acc[c] = __builtin_amdgcn_mfma_f32_16x16x32_bf16(afrag[s], b, acc[c], 0, 0, 0);
        }
    }

#pragma unroll
    for (int c = 0; c < 8; ++c) {
        int o = c * 16 + (lane & 15);
        float bv = bias[o];
#pragma unroll
        for (int r = 0; r < 4; ++r) {
            int m = m0 + (lane >> 4) * 4 + r;
            float v = acc[c][r] + bv;
            v = (ACT == 0) ? fmaxf(v, 0.f) : ((v > 0.f) ? v : expm1f(v));
            Out[(size_t)m * 128 + o] = f2bf(v);
        }
    }
}

// ---------------- layer 3 (DOUT=8) + log_softmax: 8 lanes per node ----------------
__device__ __forceinline__ float dot8(uint4 a, uint4 b, float acc) {
    const u32* pa = (const u32*)&a;
    const u32* pb = (const u32*)&b;
#pragma unroll
    for (int t = 0; t < 4; ++t) {
        acc = fmaf(__uint_as_float(pa[t] << 16), __uint_as_float(pb[t] << 16), acc);
        acc = fmaf(__uint_as_float(pa[t] & 0xffff0000u),
                   __uint_as_float(pb[t] & 0xffff0000u), acc);
    }
    return acc;
}

__global__ __launch_bounds__(256) void k_out8(const u16* Agg, const u16* Xin,
                                              const u32* Wl, const u32* Wr,
                                              const float* bias, const int* flag,
                                              void* Out, int N) {
    int t = blockIdx.x * 256 + threadIdx.x;
    int n = t >> 3;
    int o = t & 7;
    if (n >= N) return;
    float acc = bias[o];
    const uint4* ar = (const uint4*)(Agg + (size_t)n * 128);
    const uint4* xr = (const uint4*)(Xin + (size_t)n * 128);
    const uint4* wl = (const uint4*)(Wl + (size_t)o * 64);
    const uint4* wr = (const uint4*)(Wr + (size_t)o * 64);
#pragma unroll
    for (int i = 0; i < 16; ++i) {
        acc = dot8(ar[i], wl[i], acc);
        acc = dot8(xr[i], wr[i], acc);
    }
    float mx = acc;
#pragma unroll
    for (int d = 1; d < 8; d <<= 1) mx = fmaxf(mx, __shfl_xor(mx, d, 64));
    float ex = expf(acc - mx), se = ex;
#pragma unroll
    for (int d = 1; d < 8; d <<= 1) se += __shfl_xor(se, d, 64);
    float v = acc - mx - logf(se);
    if (*flag) ((float*)Out)[(size_t)n * 8 + o] = v;
    else       ((u16*)Out)[(size_t)n * 8 + o] = f2bf(v);
}

// ---------------- launch ----------------
extern "C" void kernel_launch(void* const* d_in, const int* in_sizes, int n_in,
                              void* d_out, int out_size, void* d_ws, size_t ws_size,
                              hipStream_t stream) {
    const void* x   = d_in[0];
    const int* ei   = (const int*)d_in[1];
    const int N = in_sizes[0] / 128;
    const int E = in_sizes[1] / 2;
    const int* srcv = ei;
    const int* dstv = ei + E;

    auto rnd = [](size_t b) { return (b + 255) & ~(size_t)255; };
    size_t need = rnd(256)                    // flag
                + rnd((size_t)N * 4)          // deg
                + rnd((size_t)(N + 1) * 4)    // rowptr
                + rnd(4096)                   // bsums
                + rnd((size_t)E * 4)          // adj
                + 2 * rnd((size_t)N * 256)    // X, A (packed bf16 [N,128])
                + 4 * rnd(32768) + 2 * rnd(2048) + 2 * rnd(512) + rnd(64);
    if (ws_size < need) {
        k_sentinel<<<(out_size + 255) / 256, 256, 0, stream>>>((u16*)d_out, out_size);
        return;
    }

    char* p = (char*)d_ws;
    auto carve = [&](size_t bytes) { char* r = p; p += (bytes + 255) & ~(size_t)255; return r; };
    int* flag   = (int*)carve(256);
    int* deg    = (int*)carve((size_t)N * 4);
    int* rowptr = (int*)carve((size_t)(N + 1) * 4);
    int* bsums  = (int*)carve(4096);
    int* adj    = (int*)carve((size_t)E * 4);
    u32* X      = (u32*)carve((size_t)N * 256);   // [N,128] packed bf16
    u32* A      = (u32*)carve((size_t)N * 256);
    u32* w1l = (u32*)carve(32768); u32* w1r = (u32*)carve(32768);
    u32* whl = (u32*)carve(32768); u32* whr = (u32*)carve(32768);
    u32* w2l = (u32*)carve(2048);  u32* w2r = (u32*)carve(2048);
    float* bf1 = (float*)carve(512); float* bfh = (float*)carve(512);
    float* bf2 = (float*)carve(64);
    (void)n_in;

    k_detect<<<1, 64, 0, stream>>>((const u32*)x, flag);

    // canonicalize inputs to packed bf16 / f32 bias
    k_cvt<<<(N * 64 + 255) / 256, 256, 0, stream>>>(x, flag, X, N * 64);
    k_cvt<<<32, 256, 0, stream>>>(d_in[3], flag, w1l, 8192);
    k_cvt<<<32, 256, 0, stream>>>(d_in[5], flag, w1r, 8192);
    k_cvt<<<32, 256, 0, stream>>>(d_in[6], flag, whl, 8192);
    k_cvt<<<32, 256, 0, stream>>>(d_in[8], flag, whr, 8192);
    k_cvt<<<2, 256, 0, stream>>>(d_in[9],  flag, w2l, 512);
    k_cvt<<<2, 256, 0, stream>>>(d_in[11], flag, w2r, 512);
    k_cvt_bias<<<1, 128, 0, stream>>>(d_in[4],  flag, bf1, 128);
    k_cvt_bias<<<1, 128, 0, stream>>>(d_in[7],  flag, bfh, 128);
    k_cvt_bias<<<1, 128, 0, stream>>>(d_in[10], flag, bf2, 8);

    // CSR
    hipMemsetAsync(deg, 0, (size_t)N * 4, stream);
    int nb = (N + 511) / 512;
    k_deg<<<(E + 255) / 256, 256, 0, stream>>>(dstv, deg, E, N);
    k_scan1<<<nb, 512, 0, stream>>>(deg, rowptr, bsums, N);
    k_scan2<<<1, 128, 0, stream>>>(bsums, nb);
    k_scan3<<<nb, 512, 0, stream>>>(rowptr, bsums, N, E);
    k_fill<<<(E + 255) / 256, 256, 0, stream>>>(srcv, dstv, rowptr, deg, adj, E, N);

    int aggBlocks = (int)(((size_t)N * 64 + 255) / 256);
    int gemmBlocks = ((N + 15) / 16 + 3) / 4;

    // L1: A=mean(X); h1=relu(A@W1l^T+b1+X@W1r^T) -> X (own-rows aliasing, safe)
    k_aggregate<<<aggBlocks, 256, 0, stream>>>(X, rowptr, adj, A, N, E);
    k_gemm128<0><<<gemmBlocks, 256, 0, stream>>>((const u16*)A, (const u16*)X, w1l, w1r, bf1, (u16*)X, N);
    // L2: A=mean(h1=X); h2=elu(A@Whl^T+bh+X@Whr^T) -> X
    k_aggregate<<<aggBlocks, 256, 0, stream>>>(X, rowptr, adj, A, N, E);
    k_gemm128<1><<<gemmBlocks, 256, 0, stream>>>((const u16*)A, (const u16*)X, whl, whr, bfh, (u16*)X, N);
    // L3: A=mean(h2=X); out = log_softmax(A@W2l^T+b2+X@W2r^T)
    k_aggregate<<<aggBlocks, 256, 0, stream>>>(X, rowptr, adj, A, N, E);
    k_out8<<<(int)(((size_t)N * 8 + 255) / 256), 256, 0, stream>>>(
        (const u16*)A, (const u16*)X, w2l, w2r, bf2, flag, d_out, N);
}

// Round 4
// 379.830 us; speedup vs baseline: 1.4346x; 1.4346x over previous
//
#include <hip/hip_runtime.h>

typedef unsigned int u32;
typedef unsigned short u16;
typedef short bf16x8 __attribute__((ext_vector_type(8)));   // 8 bf16 (4 VGPRs)
typedef float f32x4 __attribute__((ext_vector_type(4)));    // MFMA accumulator

__device__ __forceinline__ float bf2f(u16 h) { return __uint_as_float(((u32)h) << 16); }
__device__ __forceinline__ u16 f2bf(float f) {
    u32 u = __float_as_uint(f);
    return (u16)((u + 0x7fffu + ((u >> 16) & 1u)) >> 16);   // RNE
}

// ---------------- diagnostic fallback: ws too small ----------------
__global__ __launch_bounds__(256) void k_sentinel(u16* out, int n) {
    int i = blockIdx.x * 256 + threadIdx.x;
    if (i < n) out[i] = f2bf(-7.0f);
}

// ---------------- dtype detection: flag=0 bf16-packed, flag=1 f32 ----------------
__global__ void k_detect(const u32* x, int* flag) {
    int lane = threadIdx.x;  // 64 threads
    int c = 0;
    for (int j = 0; j < 4; ++j) {
        u32 u = x[lane * 4 + j];
        u32 e = (u >> 7) & 0xffu;
        if ((e >= 0x30u && e <= 0x47u) || ((u & 0x7fffu) == 0u)) ++c;
    }
    for (int d = 32; d; d >>= 1) c += __shfl_down(c, d, 64);
    if (lane == 0) *flag = (c < 128) ? 1 : 0;
}

// ---------------- converters into canonical packed-bf16 / f32 ----------------
__global__ __launch_bounds__(256) void k_cvt(const void* src, const int* flag,
                                             u32* dst, int n) {  // n = u32 words out
    int i = blockIdx.x * 256 + threadIdx.x;
    if (i >= n) return;
    if (*flag) {
        const float* s = (const float*)src;
        dst[i] = (u32)f2bf(s[2 * i]) | ((u32)f2bf(s[2 * i + 1]) << 16);
    } else {
        dst[i] = ((const u32*)src)[i];
    }
}

__global__ __launch_bounds__(128) void k_cvt_bias(const void* src, const int* flag,
                                                  float* dst, int n) {
    int i = threadIdx.x;
    if (i >= n) return;
    if (*flag) dst[i] = ((const float*)src)[i];
    else       dst[i] = bf2f(((const u16*)src)[i]);
}

// ---------------- CSR build ----------------
__global__ __launch_bounds__(256) void k_deg(const int* dstv, int* deg, int E, int N) {
    int e = blockIdx.x * 256 + threadIdx.x;
    if (e >= E) return;
    int d = dstv[e]; d = min(max(d, 0), N - 1);
    atomicAdd(&deg[d], 1);
}

__global__ __launch_bounds__(512) void k_scan1(const int* deg, int* rowptr,
                                               int* bsums, int N) {
    __shared__ int sm[512];
    int i = blockIdx.x * 512 + threadIdx.x;
    int v = (i < N) ? deg[i] : 0;
    sm[threadIdx.x] = v;
    __syncthreads();
    for (int off = 1; off < 512; off <<= 1) {
        int t = (threadIdx.x >= off) ? sm[threadIdx.x - off] : 0;
        __syncthreads();
        sm[threadIdx.x] += t;
        __syncthreads();
    }
    if (i < N) rowptr[i] = sm[threadIdx.x] - v;            // exclusive
    if (threadIdx.x == 511) bsums[blockIdx.x] = sm[511];
}

__global__ __launch_bounds__(128) void k_scan2(int* bsums, int nb) {
    __shared__ int sm[128];
    int v = (threadIdx.x < nb) ? bsums[threadIdx.x] : 0;
    sm[threadIdx.x] = v;
    __syncthreads();
    for (int off = 1; off < 128; off <<= 1) {
        int t = (threadIdx.x >= off) ? sm[threadIdx.x - off] : 0;
        __syncthreads();
        sm[threadIdx.x] += t;
        __syncthreads();
    }
    if (threadIdx.x < nb) bsums[threadIdx.x] = sm[threadIdx.x] - v;  // exclusive
}

__global__ __launch_bounds__(512) void k_scan3(int* rowptr, const int* bsums,
                                               int N, int E) {
    int i = blockIdx.x * 512 + threadIdx.x;
    if (i < N) rowptr[i] += bsums[blockIdx.x];
    if (i == 0) rowptr[N] = E;
}

// deg doubles as countdown cursor (any slot order is fine for mean)
__global__ __launch_bounds__(256) void k_fill(const int* srcv, const int* dstv,
                                              const int* rowptr, int* deg,
                                              int* adj, int E, int N) {
    int e = blockIdx.x * 256 + threadIdx.x;
    if (e >= E) return;
    int d = dstv[e]; d = min(max(d, 0), N - 1);
    int slot = atomicSub(&deg[d], 1) - 1;
    int idx = rowptr[d] + slot;
    idx = min(max(idx, 0), E - 1);   // clamp: CSR bug => finite-wrong, not NaN
    adj[idx] = srcv[e];
}

// ---------------- mean aggregation: one wave per node, 4 neighbors in parallel ----
// F rows are 256 B = 16 uint4. 16-lane group g loads neighbor (beg+g+4t)'s row
// (lane l -> uint4 l). Unroll 2 -> 8 independent 16B loads in flight per wave.
__device__ __forceinline__ void acc8(uint4 u, float* s) {
    const u32* pu = (const u32*)&u;
#pragma unroll
    for (int t = 0; t < 4; ++t) {
        s[2 * t]     += __uint_as_float(pu[t] << 16);
        s[2 * t + 1] += __uint_as_float(pu[t] & 0xffff0000u);
    }
}

__global__ __launch_bounds__(256) void k_aggregate(const uint4* F, const int* rowptr,
                                                   const int* adj, uint4* A,
                                                   int N, int E) {
    int wid = (int)((blockIdx.x * 256u + threadIdx.x) >> 6);
    int lane = threadIdx.x & 63;
    if (wid >= N) return;
    int beg = rowptr[wid], end = rowptr[wid + 1];
    beg = min(max(beg, 0), E);
    end = min(max(end, beg), E);
    int g = lane >> 4, l = lane & 15;
    float s[8] = {0.f, 0.f, 0.f, 0.f, 0.f, 0.f, 0.f, 0.f};
    int j = beg + g;
    for (; j + 4 < end; j += 8) {
        int a0 = min(max(adj[j], 0), N - 1);
        int a1 = min(max(adj[j + 4], 0), N - 1);
        uint4 u0 = F[(size_t)a0 * 16 + l];
        uint4 u1 = F[(size_t)a1 * 16 + l];
        acc8(u0, s);
        acc8(u1, s);
    }
    if (j < end) {
        int a0 = min(max(adj[j], 0), N - 1);
        uint4 u0 = F[(size_t)a0 * 16 + l];
        acc8(u0, s);
    }
#pragma unroll
    for (int k = 0; k < 8; ++k) {
        s[k] += __shfl_xor(s[k], 16, 64);
        s[k] += __shfl_xor(s[k], 32, 64);
    }
    if (g == 0) {
        float inv = 1.f / fmaxf((float)(end - beg), 1.f);
        uint4 r; u32* pr = (u32*)&r;
#pragma unroll
        for (int t = 0; t < 4; ++t)
            pr[t] = (u32)f2bf(s[2 * t] * inv) | ((u32)f2bf(s[2 * t + 1] * inv) << 16);
        A[(size_t)wid * 16 + l] = r;
    }
}

// ---------------- fused SAGE GEMM: h = act(Agg@Wl^T + b + Xin@Wr^T) ----------------
// One wave per 16-node tile; K=256 (agg||x vs Wl||Wr), 8 col-tiles.
// Each wave reads only its own 16 rows fully into regs before storing those same
// rows -> Out may alias Agg or Xin. (No __restrict__: aliasing is intentional.)
template <int ACT>  // 0 = relu, 1 = elu
__global__ __launch_bounds__(256) void k_gemm128(const u16* Agg, const u16* Xin,
                                                 const u32* Wl, const u32* Wr,
                                                 const float* bias, u16* Out, int N) {
    int tile = blockIdx.x * 4 + (threadIdx.x >> 6);
    int lane = threadIdx.x & 63;
    int m0 = tile * 16;
    if (m0 >= N) return;
    int mrow = m0 + (lane & 15);
    int kq = (lane >> 4) * 8;

    bf16x8 afrag[8];
#pragma unroll
    for (int s = 0; s < 8; ++s) {
        int k = s * 32 + kq;
        const u16* p = (k < 128) ? (Agg + (size_t)mrow * 128 + k)
                                 : (Xin + (size_t)mrow * 128 + (k - 128));
        afrag[s] = *(const bf16x8*)p;
    }

    f32x4 acc[8];
#pragma unroll
    for (int c = 0; c < 8; ++c) acc[c] = (f32x4){0.f, 0.f, 0.f, 0.f};

#pragma unroll
    for (int c = 0; c < 8; ++c) {
        int o = c * 16 + (lane & 15);
#pragma unroll
        for (int s = 0; s < 8; ++s) {
            int k = s * 32 + kq;
            const u32* p = (k < 128) ? (Wl + ((size_t)o * 128 + k) / 2)
                                     : (Wr + ((size_t)o * 128 + (k - 128)) / 2);
            bf16x8 b = *(const bf16x8*)p;
            acc[c] = __builtin_amdgcn_mfma_f32_16x16x32_bf16(afrag[s], b, acc[c], 0, 0, 0);
        }
    }

#pragma unroll
    for (int c = 0; c < 8; ++c) {
        int o = c * 16 + (lane & 15);
        float bv = bias[o];
#pragma unroll
        for (int r = 0; r < 4; ++r) {
            int m = m0 + (lane >> 4) * 4 + r;
            float v = acc[c][r] + bv;
            v = (ACT == 0) ? fmaxf(v, 0.f) : ((v > 0.f) ? v : expm1f(v));
            Out[(size_t)m * 128 + o] = f2bf(v);
        }
    }
}

// ---------------- layer 3: y = h2@W2l^T, r = h2@W2r^T + b  (both [N,8] f32) -------
__device__ __forceinline__ float dot8(uint4 a, uint4 b, float acc) {
    const u32* pa = (const u32*)&a;
    const u32* pb = (const u32*)&b;
#pragma unroll
    for (int t = 0; t < 4; ++t) {
        acc = fmaf(__uint_as_float(pa[t] << 16), __uint_as_float(pb[t] << 16), acc);
        acc = fmaf(__uint_as_float(pa[t] & 0xffff0000u),
                   __uint_as_float(pb[t] & 0xffff0000u), acc);
    }
    return acc;
}

__global__ __launch_bounds__(256) void k_lin8(const u16* Xin, const u32* Wl,
                                              const u32* Wr, const float* bias,
                                              float* Y, float* R, int N) {
    int t = blockIdx.x * 256 + threadIdx.x;
    int n = t >> 3;
    int o = t & 7;
    if (n >= N) return;
    const uint4* xr = (const uint4*)(Xin + (size_t)n * 128);
    const uint4* wl = (const uint4*)(Wl + (size_t)o * 64);
    const uint4* wr = (const uint4*)(Wr + (size_t)o * 64);
    float al = 0.f, ar = bias[o];
#pragma unroll
    for (int i = 0; i < 16; ++i) {
        uint4 xv = xr[i];
        al = dot8(xv, wl[i], al);
        ar = dot8(xv, wr[i], ar);
    }
    Y[(size_t)n * 8 + o] = al;
    R[(size_t)n * 8 + o] = ar;
}

// mean-aggregate Y (f32 [N,8], 1.6 MB -> L2-resident) + r + log_softmax.
// 8 lanes per node, lane o handles channel o; unroll 2 for MLP.
__global__ __launch_bounds__(256) void k_agg8sm(const float* Y, const float* R,
                                                const int* rowptr, const int* adj,
                                                const int* flag, void* Out,
                                                int N, int E) {
    int t = blockIdx.x * 256 + threadIdx.x;
    int n = t >> 3;
    int o = t & 7;
    if (n >= N) return;
    int beg = rowptr[n], end = rowptr[n + 1];
    beg = min(max(beg, 0), E);
    end = min(max(end, beg), E);
    float s = 0.f;
    int j = beg;
    for (; j + 1 < end; j += 2) {
        int a0 = min(max(adj[j], 0), N - 1);
        int a1 = min(max(adj[j + 1], 0), N - 1);
        s += Y[(size_t)a0 * 8 + o];
        s += Y[(size_t)a1 * 8 + o];
    }
    if (j < end) {
        int a0 = min(max(adj[j], 0), N - 1);
        s += Y[(size_t)a0 * 8 + o];
    }
    float acc = s / fmaxf((float)(end - beg), 1.f) + R[(size_t)n * 8 + o];
    float mx = acc;
#pragma unroll
    for (int d = 1; d < 8; d <<= 1) mx = fmaxf(mx, __shfl_xor(mx, d, 64));
    float ex = expf(acc - mx), se = ex;
#pragma unroll
    for (int d = 1; d < 8; d <<= 1) se += __shfl_xor(se, d, 64);
    float v = acc - mx - logf(se);
    if (*flag) ((float*)Out)[(size_t)n * 8 + o] = v;
    else       ((u16*)Out)[(size_t)n * 8 + o] = f2bf(v);
}

// ---------------- launch ----------------
extern "C" void kernel_launch(void* const* d_in, const int* in_sizes, int n_in,
                              void* d_out, int out_size, void* d_ws, size_t ws_size,
                              hipStream_t stream) {
    const void* x   = d_in[0];
    const int* ei   = (const int*)d_in[1];
    const int N = in_sizes[0] / 128;
    const int E = in_sizes[1] / 2;
    const int* srcv = ei;
    const int* dstv = ei + E;

    auto rnd = [](size_t b) { return (b + 255) & ~(size_t)255; };
    size_t need = rnd(256)                    // flag
                + rnd((size_t)N * 4)          // deg
                + rnd((size_t)(N + 1) * 4)    // rowptr
                + rnd(4096)                   // bsums
                + rnd((size_t)E * 4)          // adj
                + 2 * rnd((size_t)N * 256)    // X, A (packed bf16 [N,128])
                + 4 * rnd(32768) + 2 * rnd(2048) + 2 * rnd(512) + rnd(64);
    if (ws_size < need) {
        k_sentinel<<<(out_size + 255) / 256, 256, 0, stream>>>((u16*)d_out, out_size);
        return;
    }

    char* p = (char*)d_ws;
    auto carve = [&](size_t bytes) { char* r = p; p += (bytes + 255) & ~(size_t)255; return r; };
    int* flag   = (int*)carve(256);
    int* deg    = (int*)carve((size_t)N * 4);
    int* rowptr = (int*)carve((size_t)(N + 1) * 4);
    int* bsums  = (int*)carve(4096);
    int* adj    = (int*)carve((size_t)E * 4);
    u32* X      = (u32*)carve((size_t)N * 256);   // [N,128] packed bf16
    u32* A      = (u32*)carve((size_t)N * 256);   // agg buffer; dead in layer 3
    u32* w1l = (u32*)carve(32768); u32* w1r = (u32*)carve(32768);
    u32* whl = (u32*)carve(32768); u32* whr = (u32*)carve(32768);
    u32* w2l = (u32*)carve(2048);  u32* w2r = (u32*)carve(2048);
    float* bf1 = (float*)carve(512); float* bfh = (float*)carve(512);
    float* bf2 = (float*)carve(64);
    // layer-3 Y/R ([N,8] f32 = 1.6 MB each) live in the dead A buffer (12.8 MB)
    float* Y = (float*)A;
    float* R = Y + (size_t)N * 8;
    (void)n_in;

    k_detect<<<1, 64, 0, stream>>>((const u32*)x, flag);

    // canonicalize inputs to packed bf16 / f32 bias
    k_cvt<<<(N * 64 + 255) / 256, 256, 0, stream>>>(x, flag, X, N * 64);
    k_cvt<<<32, 256, 0, stream>>>(d_in[3], flag, w1l, 8192);
    k_cvt<<<32, 256, 0, stream>>>(d_in[5], flag, w1r, 8192);
    k_cvt<<<32, 256, 0, stream>>>(d_in[6], flag, whl, 8192);
    k_cvt<<<32, 256, 0, stream>>>(d_in[8], flag, whr, 8192);
    k_cvt<<<2, 256, 0, stream>>>(d_in[9],  flag, w2l, 512);
    k_cvt<<<2, 256, 0, stream>>>(d_in[11], flag, w2r, 512);
    k_cvt_bias<<<1, 128, 0, stream>>>(d_in[4],  flag, bf1, 128);
    k_cvt_bias<<<1, 128, 0, stream>>>(d_in[7],  flag, bfh, 128);
    k_cvt_bias<<<1, 128, 0, stream>>>(d_in[10], flag, bf2, 8);

    // CSR
    hipMemsetAsync(deg, 0, (size_t)N * 4, stream);
    int nb = (N + 511) / 512;
    k_deg<<<(E + 255) / 256, 256, 0, stream>>>(dstv, deg, E, N);
    k_scan1<<<nb, 512, 0, stream>>>(deg, rowptr, bsums, N);
    k_scan2<<<1, 128, 0, stream>>>(bsums, nb);
    k_scan3<<<nb, 512, 0, stream>>>(rowptr, bsums, N, E);
    k_fill<<<(E + 255) / 256, 256, 0, stream>>>(srcv, dstv, rowptr, deg, adj, E, N);

    int aggBlocks = (int)(((size_t)N * 64 + 255) / 256);
    int gemmBlocks = ((N + 15) / 16 + 3) / 4;
    int perNode8 = (int)(((size_t)N * 8 + 255) / 256);

    // L1: A=mean(X); h1=relu(A@W1l^T+b1+X@W1r^T) -> X (own-rows aliasing, safe)
    k_aggregate<<<aggBlocks, 256, 0, stream>>>((const uint4*)X, rowptr, adj, (uint4*)A, N, E);
    k_gemm128<0><<<gemmBlocks, 256, 0, stream>>>((const u16*)A, (const u16*)X, w1l, w1r, bf1, (u16*)X, N);
    // L2: A=mean(h1=X); h2=elu(A@Whl^T+bh+X@Whr^T) -> X
    k_aggregate<<<aggBlocks, 256, 0, stream>>>((const uint4*)X, rowptr, adj, (uint4*)A, N, E);
    k_gemm128<1><<<gemmBlocks, 256, 0, stream>>>((const u16*)A, (const u16*)X, whl, whr, bfh, (u16*)X, N);
    // L3 (linearity): y=h2@W2l^T, r=h2@W2r^T+b2; out = log_softmax(mean_agg(y)+r)
    k_lin8<<<perNode8, 256, 0, stream>>>((const u16*)X, w2l, w2r, bf2, Y, R, N);
    k_agg8sm<<<perNode8, 256, 0, stream>>>(Y, R, rowptr, adj, flag, d_out, N, E);
}